// Round 10
// baseline (214.893 us; speedup 1.0000x reference)
//
#include <hip/hip_runtime.h>
#include <math.h>

#define DIM 128
#define NH 8
#define LN_EPS 1e-5f
#define NEGINF -3.0e38f

using bf16x8 = __attribute__((ext_vector_type(8))) short;
using f32x4  = __attribute__((ext_vector_type(4))) float;

__device__ __forceinline__ float prelu_f(float x, float al) { return x >= 0.f ? x : al * x; }

__device__ __forceinline__ short f2bf(float f) {
    unsigned u = __float_as_uint(f);
    unsigned r = (u + 0x7fffu + ((u >> 16) & 1u)) >> 16;
    return (short)r;
}
__device__ __forceinline__ float bflo(unsigned u) { return __uint_as_float(u << 16); }
__device__ __forceinline__ float bfhi(unsigned u) { return __uint_as_float(u & 0xffff0000u); }

__device__ __forceinline__ unsigned cvt_pk_bf16(float lo, float hi) {
    unsigned r;
    asm("v_cvt_pk_bf16_f32 %0, %1, %2" : "=v"(r) : "v"(lo), "v"(hi));
    return r;
}

// ds_swizzle xor within 32-lane halves (BitMode)
__device__ __forceinline__ float swz_xor1(float x) {
    return __int_as_float(__builtin_amdgcn_ds_swizzle(__float_as_int(x), 0x041F));
}
__device__ __forceinline__ float swz_xor2(float x) {
    return __int_as_float(__builtin_amdgcn_ds_swizzle(__float_as_int(x), 0x081F));
}
__device__ __forceinline__ float swz_xor16(float x) {
    return __int_as_float(__builtin_amdgcn_ds_swizzle(__float_as_int(x), 0x401F));
}
__device__ __forceinline__ float swz_xor32(float x) {
    return __shfl_xor(x, 32);
}

// ------------------------------------------------------------------
// Setup: pack 4 weight matrices into MFMA B-frag bf16 order (blocks 0..31)
// + histogram of query_idx (blocks 32..1055).
// ------------------------------------------------------------------
__global__ __launch_bounds__(256) void setup_kernel(
    const float* __restrict__ W0, const float* __restrict__ W1,
    const float* __restrict__ W2, const float* __restrict__ W3,
    short* __restrict__ P0, short* __restrict__ P1,
    short* __restrict__ P2, short* __restrict__ P3,
    const int* __restrict__ qidx, int* __restrict__ counts, int E)
{
    if (blockIdx.x < 32) {
        const int id = blockIdx.x * 256 + threadIdx.x;   // 8192 total
        const int mat = id >> 11;
        const int rem = id & 2047;
        const int ks = rem >> 9;
        const int ct = (rem >> 6) & 7;
        const int lane = rem & 63;
        const int lr = lane & 15, lg = lane >> 4;
        const float* W = mat == 0 ? W0 : mat == 1 ? W1 : mat == 2 ? W2 : W3;
        short* P = mat == 0 ? P0 : mat == 1 ? P1 : mat == 2 ? P2 : P3;
        short v[8];
        #pragma unroll
        for (int r = 0; r < 8; ++r)
            v[r] = f2bf(W[(ks * 32 + lg * 8 + r) * DIM + ct * 16 + lr]);
        *(bf16x8*)&P[(size_t)((ks * 8 + ct) * 64 + lane) * 8] = *(bf16x8*)v;
    } else {
        const int b = blockIdx.x - 32;
        for (int e = b * 256 + threadIdx.x; e < E; e += 1024 * 256)
            atomicAdd(&counts[qidx[e]], 1);
    }
}

// ------------------------------------------------------------------
// Fused projections. unroll 2 on the ct loop -> two independent MFMA
// accumulator chains in flight (latency-bound fix).
// Blocks [0,nb): query -> QV16 + attnqq4. Blocks [nb,nb+mb): kv -> KV16.
// ------------------------------------------------------------------
__global__ __launch_bounds__(256) void proj_all_mfma(
    const float* __restrict__ query,
    const float* __restrict__ key, const float* __restrict__ value,
    const short* __restrict__ Wqp, const short* __restrict__ Wkp, const short* __restrict__ Wvp,
    const float* __restrict__ bq, const float* __restrict__ bk, const float* __restrict__ bv,
    const float* __restrict__ avec, const float* __restrict__ alpha_p,
    short* __restrict__ QV16, float* __restrict__ attnqq4,
    short* __restrict__ KV16, int N, int M, int nb)
{
    __shared__ unsigned lds[4][16][66];
    const int wid = threadIdx.x >> 6, lane = threadIdx.x & 63;
    const int lr = lane & 15, lg = lane >> 4;
    const bool evenlane = (lane & 1) == 0;

    if ((int)blockIdx.x < nb) {
        const int row0 = ((int)blockIdx.x * 4 + wid) * 16;
        if (row0 >= N) return;
        const int arow = row0 + lr;
        const bool rowok = arow < N;

        bf16x8 afrag[4];
        #pragma unroll
        for (int ks = 0; ks < 4; ++ks) {
            float t[8] = {0.f,0.f,0.f,0.f,0.f,0.f,0.f,0.f};
            if (rowok) {
                *(float4*)&t[0] = *(const float4*)&query[(size_t)arow * DIM + ks * 32 + lg * 8];
                *(float4*)&t[4] = *(const float4*)&query[(size_t)arow * DIM + ks * 32 + lg * 8 + 4];
            }
            union { bf16x8 v; unsigned u[4]; } a;
            a.u[0] = cvt_pk_bf16(t[0], t[1]);
            a.u[1] = cvt_pk_bf16(t[2], t[3]);
            a.u[2] = cvt_pk_bf16(t[4], t[5]);
            a.u[3] = cvt_pk_bf16(t[6], t[7]);
            afrag[ks] = a.v;
        }
        const float al = alpha_p[0];
        unsigned* qvout = (unsigned*)QV16;

        // pass 1: Q & K chains; attnqq4 partials; stage packed Q
        #pragma unroll 2
        for (int ct = 0; ct < 8; ++ct) {
            f32x4 aq = (f32x4)0.f, ak = (f32x4)0.f;
            #pragma unroll
            for (int ks = 0; ks < 4; ++ks) {
                const size_t bo = (size_t)((ks * 8 + ct) * 64 + lane) * 8;
                aq = __builtin_amdgcn_mfma_f32_16x16x32_bf16(afrag[ks], *(const bf16x8*)&Wqp[bo], aq, 0, 0, 0);
                ak = __builtin_amdgcn_mfma_f32_16x16x32_bf16(afrag[ks], *(const bf16x8*)&Wkp[bo], ak, 0, 0, 0);
            }
            const int col = ct * 16 + lr;
            const float bqv = bq[col], bkv = bk[col], av = avec[col];
            #pragma unroll
            for (int r = 0; r < 4; ++r) {
                const int row = lg * 4 + r;
                const float qv = aq[r] + bqv;
                const float kv = ak[r] + bkv;
                float part = av * prelu_f(qv + kv, al);
                part += swz_xor1(part);
                part += swz_xor2(part);     // every lane holds its 4-group sum
                const int grow = row0 + row;
                if ((lr & 3) == 0 && grow < N)
                    attnqq4[(size_t)grow * 32 + ct * 4 + (lr >> 2)] = part;
                const float qn = swz_xor1(qv);
                if (evenlane) lds[wid][row][ct * 8 + (lr >> 1)] = cvt_pk_bf16(qv, qn);
            }
        }
        #pragma unroll
        for (int rr = 0; rr < 16; ++rr) {
            const int grow = row0 + rr;
            if (grow < N) qvout[(size_t)grow * 128 + lane] = lds[wid][rr][lane];
        }

        // pass 2: Vq chain; stage packed V
        #pragma unroll 2
        for (int ct = 0; ct < 8; ++ct) {
            f32x4 acv = (f32x4)0.f;
            #pragma unroll
            for (int ks = 0; ks < 4; ++ks) {
                const size_t bo = (size_t)((ks * 8 + ct) * 64 + lane) * 8;
                acv = __builtin_amdgcn_mfma_f32_16x16x32_bf16(afrag[ks], *(const bf16x8*)&Wvp[bo], acv, 0, 0, 0);
            }
            const int col = ct * 16 + lr;
            const float bvv = bv[col];
            #pragma unroll
            for (int r = 0; r < 4; ++r) {
                const int row = lg * 4 + r;
                const float vv = acv[r] + bvv;
                const float vn = swz_xor1(vv);
                if (evenlane) lds[wid][row][ct * 8 + (lr >> 1)] = cvt_pk_bf16(vv, vn);
            }
        }
        #pragma unroll
        for (int rr = 0; rr < 16; ++rr) {
            const int grow = row0 + rr;
            if (grow < N) qvout[(size_t)grow * 128 + 64 + lane] = lds[wid][rr][lane];
        }
    } else {
        const int row0 = (((int)blockIdx.x - nb) * 4 + wid) * 16;
        if (row0 >= M) return;
        const int arow = row0 + lr;
        const bool rowok = arow < M;
        unsigned* kvout = (unsigned*)KV16;

        // pass 1: K = key @ Wk
        {
            bf16x8 afK[4];
            #pragma unroll
            for (int ks = 0; ks < 4; ++ks) {
                float t[8] = {0.f,0.f,0.f,0.f,0.f,0.f,0.f,0.f};
                if (rowok) {
                    *(float4*)&t[0] = *(const float4*)&key[(size_t)arow * DIM + ks * 32 + lg * 8];
                    *(float4*)&t[4] = *(const float4*)&key[(size_t)arow * DIM + ks * 32 + lg * 8 + 4];
                }
                union { bf16x8 v; unsigned u[4]; } a;
                a.u[0] = cvt_pk_bf16(t[0], t[1]);
                a.u[1] = cvt_pk_bf16(t[2], t[3]);
                a.u[2] = cvt_pk_bf16(t[4], t[5]);
                a.u[3] = cvt_pk_bf16(t[6], t[7]);
                afK[ks] = a.v;
            }
            #pragma unroll 2
            for (int ct = 0; ct < 8; ++ct) {
                f32x4 ack = (f32x4)0.f;
                #pragma unroll
                for (int ks = 0; ks < 4; ++ks) {
                    const size_t bo = (size_t)((ks * 8 + ct) * 64 + lane) * 8;
                    ack = __builtin_amdgcn_mfma_f32_16x16x32_bf16(afK[ks], *(const bf16x8*)&Wkp[bo], ack, 0, 0, 0);
                }
                const int col = ct * 16 + lr;
                const float bkv = bk[col];
                #pragma unroll
                for (int r = 0; r < 4; ++r) {
                    const int row = lg * 4 + r;
                    const float kv = ack[r] + bkv;
                    const float kn = swz_xor1(kv);
                    if (evenlane) lds[wid][row][ct * 8 + (lr >> 1)] = cvt_pk_bf16(kv, kn);
                }
            }
            #pragma unroll
            for (int rr = 0; rr < 16; ++rr) {
                const int grow = row0 + rr;
                if (grow < M) kvout[(size_t)grow * 128 + lane] = lds[wid][rr][lane];
            }
        }
        // pass 2: V = value @ Wv
        {
            bf16x8 afV[4];
            #pragma unroll
            for (int ks = 0; ks < 4; ++ks) {
                float t[8] = {0.f,0.f,0.f,0.f,0.f,0.f,0.f,0.f};
                if (rowok) {
                    *(float4*)&t[0] = *(const float4*)&value[(size_t)arow * DIM + ks * 32 + lg * 8];
                    *(float4*)&t[4] = *(const float4*)&value[(size_t)arow * DIM + ks * 32 + lg * 8 + 4];
                }
                union { bf16x8 v; unsigned u[4]; } a;
                a.u[0] = cvt_pk_bf16(t[0], t[1]);
                a.u[1] = cvt_pk_bf16(t[2], t[3]);
                a.u[2] = cvt_pk_bf16(t[4], t[5]);
                a.u[3] = cvt_pk_bf16(t[6], t[7]);
                afV[ks] = a.v;
            }
            #pragma unroll 2
            for (int ct = 0; ct < 8; ++ct) {
                f32x4 acv = (f32x4)0.f;
                #pragma unroll
                for (int ks = 0; ks < 4; ++ks) {
                    const size_t bo = (size_t)((ks * 8 + ct) * 64 + lane) * 8;
                    acv = __builtin_amdgcn_mfma_f32_16x16x32_bf16(afV[ks], *(const bf16x8*)&Wvp[bo], acv, 0, 0, 0);
                }
                const int col = ct * 16 + lr;
                const float bvv = bv[col];
                #pragma unroll
                for (int r = 0; r < 4; ++r) {
                    const int row = lg * 4 + r;
                    const float vv = acv[r] + bvv;
                    const float vn = swz_xor1(vv);
                    if (evenlane) lds[wid][row][ct * 8 + (lr >> 1)] = cvt_pk_bf16(vv, vn);
                }
            }
            #pragma unroll
            for (int rr = 0; rr < 16; ++rr) {
                const int grow = row0 + rr;
                if (grow < M) kvout[(size_t)grow * 128 + 64 + lane] = lds[wid][rr][lane];
            }
        }
    }
}

// ------------------------------------------------------------------
// CSR scan chain
// ------------------------------------------------------------------
__global__ __launch_bounds__(256) void scan1_kernel(const int* __restrict__ counts,
                                                    int* __restrict__ bsum, int N)
{
    __shared__ int sh[256];
    int i = blockIdx.x * 256 + threadIdx.x;
    sh[threadIdx.x] = (i < N) ? counts[i] : 0;
    __syncthreads();
    #pragma unroll
    for (int off = 128; off; off >>= 1) {
        if (threadIdx.x < off) sh[threadIdx.x] += sh[threadIdx.x + off];
        __syncthreads();
    }
    if (threadIdx.x == 0) bsum[blockIdx.x] = sh[0];
}

__global__ __launch_bounds__(256) void scan2_kernel(const int* __restrict__ bsum,
                                                    int* __restrict__ boff, int B)
{
    int t = threadIdx.x;
    if (B > 256) {
        if (t == 0) { int run = 0; for (int i = 0; i < B; ++i) { int v = bsum[i]; boff[i] = run; run += v; } }
        return;
    }
    __shared__ int sh[256];
    int v = (t < B) ? bsum[t] : 0;
    sh[t] = v;
    __syncthreads();
    for (int off = 1; off < 256; off <<= 1) {
        int x = (t >= off) ? sh[t - off] : 0;
        __syncthreads();
        sh[t] += x;
        __syncthreads();
    }
    if (t < B) boff[t] = sh[t] - v;
}

__global__ __launch_bounds__(256) void scan3_kernel(const int* __restrict__ counts,
                                                    const int* __restrict__ boff,
                                                    int* __restrict__ offsets,
                                                    int* __restrict__ cursor,
                                                    int N, int E)
{
    __shared__ int sh[256];
    int t = threadIdx.x;
    int i = blockIdx.x * 256 + t;
    int v = (i < N) ? counts[i] : 0;
    sh[t] = v;
    __syncthreads();
    for (int off = 1; off < 256; off <<= 1) {
        int x = (t >= off) ? sh[t - off] : 0;
        __syncthreads();
        sh[t] += x;
        __syncthreads();
    }
    int base = boff[blockIdx.x];
    if (i < N) {
        int o = base + sh[t] - v;
        offsets[i] = o;
        cursor[i] = o;
    }
    if (i == 0) offsets[N] = E;
}

__global__ void fill_kernel(const int* __restrict__ qidx, const int* __restrict__ kidx,
                            int* __restrict__ cursor, int* __restrict__ ksorted, int E)
{
    for (int e = blockIdx.x * blockDim.x + threadIdx.x; e < E; e += gridDim.x * blockDim.x) {
        int q = qidx[e];
        int pos = atomicAdd(&cursor[q], 1);
        ksorted[pos] = kidx[e];
    }
}

// ------------------------------------------------------------------
// Edge aggregation v8: one node per wave, 4 edge slots.
// lane = e(2 bits, lane>>4) | sub(4 bits). 8 dims/lane, head = sub>>1.
// 8 KV gather loads in flight (4 slots x K,V) + 1-deep pipeline.
// Merge rounds: xor16 (ds_swizzle) then xor32 (shfl).
// ------------------------------------------------------------------
__global__ __launch_bounds__(256) void edge_agg_kernel(
    const short* __restrict__ QV16, const float* __restrict__ attnqq4,
    const short* __restrict__ KV16,
    const int* __restrict__ ksorted, const int* __restrict__ offsets,
    const float* __restrict__ avec, const float* __restrict__ alpha_p,
    short* __restrict__ msgn16, int N)
{
    const int lane = threadIdx.x & 63;
    const int wid  = threadIdx.x >> 6;
    const int e    = lane >> 4;         // edge slot 0..3
    const int sub  = lane & 15;         // 8-dim chunk
    const int h    = sub >> 1;          // head

    const float al = alpha_p[0];
    const float r  = (1.f - al) / (1.f + al);
    const float s1 = (1.f + al) * 0.5f;

    float c[8];
    {
        const float4 a0 = *(const float4*)&avec[sub * 8];
        const float4 a1 = *(const float4*)&avec[sub * 8 + 4];
        c[0] = a0.x * s1; c[1] = a0.y * s1; c[2] = a0.z * s1; c[3] = a0.w * s1;
        c[4] = a1.x * s1; c[5] = a1.y * s1; c[6] = a1.z * s1; c[7] = a1.w * s1;
    }

    const int wavesTotal = gridDim.x * 4;

    for (int n = blockIdx.x * 4 + wid; n < N; n += wavesTotal) {
        float q[8];
        {
            unsigned qd[4];
            *(uint4*)qd = *(const uint4*)&QV16[(size_t)n * 256 + sub * 8];
            #pragma unroll
            for (int j = 0; j < 4; ++j) { q[2*j] = bflo(qd[j]); q[2*j+1] = bfhi(qd[j]); }
        }

        float acc[8];
        float den;
        if (e == 0) {
            unsigned vdi[4];
            *(uint4*)vdi = *(const uint4*)&QV16[(size_t)n * 256 + 128 + sub * 8];
            #pragma unroll
            for (int j = 0; j < 4; ++j) { acc[2*j] = bflo(vdi[j]); acc[2*j+1] = bfhi(vdi[j]); }
            den = 1.f;
        } else {
            #pragma unroll
            for (int d = 0; d < 8; ++d) acc[d] = 0.f;
            den = 0.f;
        }

        float m;
        {
            const float4 a4 = *(const float4*)&attnqq4[(size_t)n * 32 + h * 4];
            m = (a4.x + a4.y) + (a4.z + a4.w);
        }

        const int p0 = offsets[n];
        const int p1 = offsets[n + 1];
        bool div = false;

        // pipeline prologue: stage-0 loads (4 slots)
        const int idx0 = p0 + e;
        bool v0 = idx0 < p1;
        const int ki0 = v0 ? ksorted[idx0] : 0;
        unsigned kd0[4], vd0[4];
        {
            const size_t kb = (size_t)ki0 * 256 + sub * 8;
            *(uint4*)kd0 = *(const uint4*)&KV16[kb];
            *(uint4*)vd0 = *(const uint4*)&KV16[kb + 128];
        }

        for (int it = 1; __any(v0); ++it) {
            // issue next-stage loads before current compute
            const int nidx = p0 + it * 4 + e;
            const bool v1 = nidx < p1;
            const int ki1 = v1 ? ksorted[nidx] : 0;
            unsigned kd1[4], vd1[4];
            {
                const size_t kb = (size_t)ki1 * 256 + sub * 8;
                *(uint4*)kd1 = *(const uint4*)&KV16[kb];
                *(uint4*)vd1 = *(const uint4*)&KV16[kb + 128];
            }

            // compute current stage
            float sp = 0.f;
            #pragma unroll
            for (int j = 0; j < 4; ++j) {
                const float x0 = q[2*j]   + bflo(kd0[j]);
                const float x1 = q[2*j+1] + bfhi(kd0[j]);
                const float t0 = fmaf(r, __builtin_fabsf(x0), x0);
                const float t1 = fmaf(r, __builtin_fabsf(x1), x1);
                sp = fmaf(c[2*j], t0, sp);
                sp = fmaf(c[2*j+1], t1, sp);
            }
            const float sf = sp + swz_xor1(sp);   // sum head pair -> full 16-dim score
            const float s = v0 ? sf : NEGINF;
            const float d_ = s - m;

            if (__any(d_ > 8.f)) {
                div = true;
                const float nm = fmaxf(m, s);
                const float cc = __expf(m - nm);
                const float w = __expf(s - nm);
                den = den * cc + w;
                #pragma unroll
                for (int j = 0; j < 4; ++j) {
                    acc[2*j]   = fmaf(acc[2*j],   cc, w * bflo(vd0[j]));
                    acc[2*j+1] = fmaf(acc[2*j+1], cc, w * bfhi(vd0[j]));
                }
                m = nm;
            } else {
                const float w = __expf(d_);       // 0 for invalid lanes
                den += w;
                #pragma unroll
                for (int j = 0; j < 4; ++j) {
                    acc[2*j]   = fmaf(w, bflo(vd0[j]), acc[2*j]);
                    acc[2*j+1] = fmaf(w, bfhi(vd0[j]), acc[2*j+1]);
                }
            }

            // rotate
            #pragma unroll
            for (int j = 0; j < 4; ++j) { kd0[j] = kd1[j]; vd0[j] = vd1[j]; }
            v0 = v1;
        }

        // merge 4 slots: lane bit 4 (xor16, within half) then bit 5 (xor32)
        #define MERGE_ROUND(SWZ)                                    \
            {                                                       \
                const float m2 = SWZ(m);                            \
                const float den2 = SWZ(den);                        \
                const float nm = fmaxf(m, m2);                      \
                const float ca = __expf(m - nm);                    \
                const float cb = __expf(m2 - nm);                   \
                den = den * ca + den2 * cb;                         \
                _Pragma("unroll")                                   \
                for (int d = 0; d < 8; ++d)                         \
                    acc[d] = acc[d] * ca + SWZ(acc[d]) * cb;        \
                m = nm;                                             \
            }
        #define SUM_ROUND(SWZ)                                      \
            {                                                       \
                den += SWZ(den);                                    \
                _Pragma("unroll")                                   \
                for (int d = 0; d < 8; ++d) acc[d] += SWZ(acc[d]);  \
            }
        if (div) {
            MERGE_ROUND(swz_xor16);
            MERGE_ROUND(swz_xor32);
        } else {
            SUM_ROUND(swz_xor16);
            SUM_ROUND(swz_xor32);
        }
        #undef MERGE_ROUND
        #undef SUM_ROUND

        if (e == 0) {
            const float inv = 1.f / den;
            unsigned u[4];
            #pragma unroll
            for (int j = 0; j < 4; ++j)
                u[j] = cvt_pk_bf16(acc[2*j] * inv, acc[2*j+1] * inv);
            *(uint4*)&msgn16[(size_t)n * DIM + sub * 8] = *(uint4*)u;
        }
    }
}

// ------------------------------------------------------------------
// Output projection (MFMA, unroll-2 ct chains) + residual + LayerNorm.
// ------------------------------------------------------------------
__global__ __launch_bounds__(256) void out_ln_mfma(
    const short* __restrict__ msgn16, const short* __restrict__ Wpp,
    const float* __restrict__ bp, const float* __restrict__ query,
    const float* __restrict__ gamma, const float* __restrict__ beta,
    float* __restrict__ out, int N)
{
    __shared__ float ys[64][130];
    const int wid = threadIdx.x >> 6, lane = threadIdx.x & 63;
    const int rowbase = blockIdx.x * 64;
    const int row0 = rowbase + wid * 16;
    const int lr = lane & 15, lg = lane >> 4;

    if (row0 < N) {
        bf16x8 afrag[4];
        const int arow = row0 + lr;
        const bool rowok = arow < N;
        #pragma unroll
        for (int ks = 0; ks < 4; ++ks) {
            if (rowok)
                afrag[ks] = *(const bf16x8*)&msgn16[(size_t)arow * DIM + ks * 32 + lg * 8];
            else {
                bf16x8 z;
                #pragma unroll
                for (int j = 0; j < 8; ++j) z[j] = 0;
                afrag[ks] = z;
            }
        }
        #pragma unroll 2
        for (int ct = 0; ct < 8; ++ct) {
            f32x4 acc = (f32x4)0.f;
            #pragma unroll
            for (int ks = 0; ks < 4; ++ks) {
                const size_t bo = (size_t)((ks * 8 + ct) * 64 + lane) * 8;
                acc = __builtin_amdgcn_mfma_f32_16x16x32_bf16(afrag[ks], *(const bf16x8*)&Wpp[bo], acc, 0, 0, 0);
            }
            const int col = ct * 16 + lr;
            const float bpv = bp[col];
            #pragma unroll
            for (int r = 0; r < 4; ++r)
                ys[wid * 16 + lg * 4 + r][col] = acc[r] + bpv;
        }
    }
    __syncthreads();

    for (int rr = 0; rr < 16; ++rr) {
        const int r = wid * 16 + rr;
        const int grow = rowbase + r;
        if (grow >= N) break;
        const float y1 = ys[r][lane], y2 = ys[r][lane + 64];
        const float q1 = query[(size_t)grow * DIM + lane];
        const float q2 = query[(size_t)grow * DIM + lane + 64];
        const float r1 = y1 + q1, r2 = y2 + q2;
        float s = r1 + r2;
        float ss = r1 * r1 + r2 * r2;
        #pragma unroll
        for (int off = 32; off; off >>= 1) {
            s += __shfl_xor(s, off);
            ss += __shfl_xor(ss, off);
        }
        const float mu = s * (1.f / DIM);
        const float var = ss * (1.f / DIM) - mu * mu;
        const float rstd = rsqrtf(var + LN_EPS);
        out[(size_t)grow * DIM + lane] = gamma[lane] * (r1 - mu) * rstd + beta[lane];
        out[(size_t)grow * DIM + lane + 64] = gamma[lane + 64] * (r2 - mu) * rstd + beta[lane + 64];
    }
}

// ------------------------------------------------------------------
extern "C" void kernel_launch(void* const* d_in, const int* in_sizes, int n_in,
                              void* d_out, int out_size, void* d_ws, size_t ws_size,
                              hipStream_t stream) {
    const float* query = (const float*)d_in[0];
    const float* key   = (const float*)d_in[1];
    const float* value = (const float*)d_in[2];
    const int* query_idx = (const int*)d_in[3];
    const int* key_idx   = (const int*)d_in[4];
    const float* Wq = (const float*)d_in[5];
    const float* bq = (const float*)d_in[6];
    const float* Wk = (const float*)d_in[7];
    const float* bk = (const float*)d_in[8];
    const float* Wv = (const float*)d_in[9];
    const float* bv = (const float*)d_in[10];
    const float* Wp = (const float*)d_in[11];
    const float* bp = (const float*)d_in[12];
    const float* avec  = (const float*)d_in[13];
    const float* alpha = (const float*)d_in[14];
    const float* gamma = (const float*)d_in[15];
    const float* beta  = (const float*)d_in[16];
    float* out = (float*)d_out;

    const int N = in_sizes[0] / DIM;
    const int M = in_sizes[1] / DIM;
    const int E = in_sizes[3];

    // workspace layout (16B aligned)
    float* f = (float*)d_ws;
    float* attnqq4 = f; f += (size_t)N * 32;
    short* sp = (short*)f;
    short* QV16 = sp;   sp += (size_t)N * 256;
    short* KV16 = sp;   sp += (size_t)M * 256;
    short* msgn16 = sp; sp += (size_t)N * DIM;
    short* Wqp = sp;    sp += DIM * DIM;
    short* Wkp = sp;    sp += DIM * DIM;
    short* Wvp = sp;    sp += DIM * DIM;
    short* Wpp = sp;    sp += DIM * DIM;
    int* ip = (int*)(((size_t)sp + 15) & ~(size_t)15);
    int* counts  = ip;  ip += N;
    int* offsets = ip;  ip += N + 1;
    int* cursor  = ip;  ip += N;
    int* bsum    = ip;  ip += 4096;
    int* boff    = ip;  ip += 4096;
    int* ksorted = ip;  ip += E;

    const int B = (N + 255) / 256;
    const int nb = (N + 63) / 64;
    const int mb = (M + 63) / 64;

    hipMemsetAsync(counts, 0, (size_t)N * sizeof(int), stream);

    setup_kernel<<<1056, 256, 0, stream>>>(Wq, Wk, Wv, Wp, Wqp, Wkp, Wvp, Wpp,
                                           query_idx, counts, E);

    scan1_kernel<<<B, 256, 0, stream>>>(counts, bsum, N);
    scan2_kernel<<<1, 256, 0, stream>>>(bsum, boff, B);
    scan3_kernel<<<B, 256, 0, stream>>>(counts, boff, offsets, cursor, N, E);
    fill_kernel<<<1024, 256, 0, stream>>>(query_idx, key_idx, cursor, ksorted, E);

    proj_all_mfma<<<nb + mb, 256, 0, stream>>>(
        query, key, value, Wqp, Wkp, Wvp, bq, bk, bv, avec, alpha,
        QV16, attnqq4, KV16, N, M, nb);

    edge_agg_kernel<<<2048, 256, 0, stream>>>(
        QV16, attnqq4, KV16, ksorted, offsets, avec, alpha, msgn16, N);

    out_ln_mfma<<<(N + 63) / 64, 256, 0, stream>>>(
        msgn16, Wpp, bp, query, gamma, beta, out, N);
}

// Round 11
// 205.640 us; speedup vs baseline: 1.0450x; 1.0450x over previous
//
#include <hip/hip_runtime.h>
#include <math.h>

#define DIM 128
#define NH 8
#define LN_EPS 1e-5f
#define NEGINF -3.0e38f

using bf16x8 = __attribute__((ext_vector_type(8))) short;
using f32x4  = __attribute__((ext_vector_type(4))) float;

__device__ __forceinline__ float prelu_f(float x, float al) { return x >= 0.f ? x : al * x; }

__device__ __forceinline__ short f2bf(float f) {
    unsigned u = __float_as_uint(f);
    unsigned r = (u + 0x7fffu + ((u >> 16) & 1u)) >> 16;
    return (short)r;
}
__device__ __forceinline__ float bflo(unsigned u) { return __uint_as_float(u << 16); }
__device__ __forceinline__ float bfhi(unsigned u) { return __uint_as_float(u & 0xffff0000u); }

__device__ __forceinline__ unsigned cvt_pk_bf16(float lo, float hi) {
    unsigned r;
    asm("v_cvt_pk_bf16_f32 %0, %1, %2" : "=v"(r) : "v"(lo), "v"(hi));
    return r;
}

// ds_swizzle xor within 32-lane halves (BitMode)
__device__ __forceinline__ float swz_xor1(float x) {
    return __int_as_float(__builtin_amdgcn_ds_swizzle(__float_as_int(x), 0x041F));
}
__device__ __forceinline__ float swz_xor2(float x) {
    return __int_as_float(__builtin_amdgcn_ds_swizzle(__float_as_int(x), 0x081F));
}
__device__ __forceinline__ float swz_xor16(float x) {
    return __int_as_float(__builtin_amdgcn_ds_swizzle(__float_as_int(x), 0x401F));
}
__device__ __forceinline__ float swz_xor32(float x) {
    return __shfl_xor(x, 32);
}

// ------------------------------------------------------------------
// Setup: pack 4 weight matrices into MFMA B-frag bf16 order (blocks 0..31)
// + histogram of query_idx (blocks 32..1055).
// ------------------------------------------------------------------
__global__ __launch_bounds__(256) void setup_kernel(
    const float* __restrict__ W0, const float* __restrict__ W1,
    const float* __restrict__ W2, const float* __restrict__ W3,
    short* __restrict__ P0, short* __restrict__ P1,
    short* __restrict__ P2, short* __restrict__ P3,
    const int* __restrict__ qidx, int* __restrict__ counts, int E)
{
    if (blockIdx.x < 32) {
        const int id = blockIdx.x * 256 + threadIdx.x;   // 8192 total
        const int mat = id >> 11;
        const int rem = id & 2047;
        const int ks = rem >> 9;
        const int ct = (rem >> 6) & 7;
        const int lane = rem & 63;
        const int lr = lane & 15, lg = lane >> 4;
        const float* W = mat == 0 ? W0 : mat == 1 ? W1 : mat == 2 ? W2 : W3;
        short* P = mat == 0 ? P0 : mat == 1 ? P1 : mat == 2 ? P2 : P3;
        short v[8];
        #pragma unroll
        for (int r = 0; r < 8; ++r)
            v[r] = f2bf(W[(ks * 32 + lg * 8 + r) * DIM + ct * 16 + lr]);
        *(bf16x8*)&P[(size_t)((ks * 8 + ct) * 64 + lane) * 8] = *(bf16x8*)v;
    } else {
        const int b = blockIdx.x - 32;
        for (int e = b * 256 + threadIdx.x; e < E; e += 1024 * 256)
            atomicAdd(&counts[qidx[e]], 1);
    }
}

// ------------------------------------------------------------------
// Fused projections (unroll-2 ct chains). Blocks [0,nb): query ->
// QV16 + attnqq4. Blocks [nb,nb+mb): key/value -> KV16.
// ------------------------------------------------------------------
__global__ __launch_bounds__(256) void proj_all_mfma(
    const float* __restrict__ query,
    const float* __restrict__ key, const float* __restrict__ value,
    const short* __restrict__ Wqp, const short* __restrict__ Wkp, const short* __restrict__ Wvp,
    const float* __restrict__ bq, const float* __restrict__ bk, const float* __restrict__ bv,
    const float* __restrict__ avec, const float* __restrict__ alpha_p,
    short* __restrict__ QV16, float* __restrict__ attnqq4,
    short* __restrict__ KV16, int N, int M, int nb)
{
    __shared__ unsigned lds[4][16][66];
    const int wid = threadIdx.x >> 6, lane = threadIdx.x & 63;
    const int lr = lane & 15, lg = lane >> 4;
    const bool evenlane = (lane & 1) == 0;

    if ((int)blockIdx.x < nb) {
        const int row0 = ((int)blockIdx.x * 4 + wid) * 16;
        if (row0 >= N) return;
        const int arow = row0 + lr;
        const bool rowok = arow < N;

        bf16x8 afrag[4];
        #pragma unroll
        for (int ks = 0; ks < 4; ++ks) {
            float t[8] = {0.f,0.f,0.f,0.f,0.f,0.f,0.f,0.f};
            if (rowok) {
                *(float4*)&t[0] = *(const float4*)&query[(size_t)arow * DIM + ks * 32 + lg * 8];
                *(float4*)&t[4] = *(const float4*)&query[(size_t)arow * DIM + ks * 32 + lg * 8 + 4];
            }
            union { bf16x8 v; unsigned u[4]; } a;
            a.u[0] = cvt_pk_bf16(t[0], t[1]);
            a.u[1] = cvt_pk_bf16(t[2], t[3]);
            a.u[2] = cvt_pk_bf16(t[4], t[5]);
            a.u[3] = cvt_pk_bf16(t[6], t[7]);
            afrag[ks] = a.v;
        }
        const float al = alpha_p[0];
        unsigned* qvout = (unsigned*)QV16;

        // pass 1: Q & K chains; attnqq4 partials; stage packed Q
        #pragma unroll 2
        for (int ct = 0; ct < 8; ++ct) {
            f32x4 aq = (f32x4)0.f, ak = (f32x4)0.f;
            #pragma unroll
            for (int ks = 0; ks < 4; ++ks) {
                const size_t bo = (size_t)((ks * 8 + ct) * 64 + lane) * 8;
                aq = __builtin_amdgcn_mfma_f32_16x16x32_bf16(afrag[ks], *(const bf16x8*)&Wqp[bo], aq, 0, 0, 0);
                ak = __builtin_amdgcn_mfma_f32_16x16x32_bf16(afrag[ks], *(const bf16x8*)&Wkp[bo], ak, 0, 0, 0);
            }
            const int col = ct * 16 + lr;
            const float bqv = bq[col], bkv = bk[col], av = avec[col];
            #pragma unroll
            for (int r = 0; r < 4; ++r) {
                const int row = lg * 4 + r;
                const float qv = aq[r] + bqv;
                const float kv = ak[r] + bkv;
                float part = av * prelu_f(qv + kv, al);
                part += swz_xor1(part);
                part += swz_xor2(part);
                const int grow = row0 + row;
                if ((lr & 3) == 0 && grow < N)
                    attnqq4[(size_t)grow * 32 + ct * 4 + (lr >> 2)] = part;
                const float qn = swz_xor1(qv);
                if (evenlane) lds[wid][row][ct * 8 + (lr >> 1)] = cvt_pk_bf16(qv, qn);
            }
        }
        #pragma unroll
        for (int rr = 0; rr < 16; ++rr) {
            const int grow = row0 + rr;
            if (grow < N) qvout[(size_t)grow * 128 + lane] = lds[wid][rr][lane];
        }

        // pass 2: Vq chain; stage packed V
        #pragma unroll 2
        for (int ct = 0; ct < 8; ++ct) {
            f32x4 acv = (f32x4)0.f;
            #pragma unroll
            for (int ks = 0; ks < 4; ++ks) {
                const size_t bo = (size_t)((ks * 8 + ct) * 64 + lane) * 8;
                acv = __builtin_amdgcn_mfma_f32_16x16x32_bf16(afrag[ks], *(const bf16x8*)&Wvp[bo], acv, 0, 0, 0);
            }
            const int col = ct * 16 + lr;
            const float bvv = bv[col];
            #pragma unroll
            for (int r = 0; r < 4; ++r) {
                const int row = lg * 4 + r;
                const float vv = acv[r] + bvv;
                const float vn = swz_xor1(vv);
                if (evenlane) lds[wid][row][ct * 8 + (lr >> 1)] = cvt_pk_bf16(vv, vn);
            }
        }
        #pragma unroll
        for (int rr = 0; rr < 16; ++rr) {
            const int grow = row0 + rr;
            if (grow < N) qvout[(size_t)grow * 128 + 64 + lane] = lds[wid][rr][lane];
        }
    } else {
        const int row0 = (((int)blockIdx.x - nb) * 4 + wid) * 16;
        if (row0 >= M) return;
        const int arow = row0 + lr;
        const bool rowok = arow < M;
        unsigned* kvout = (unsigned*)KV16;

        // pass 1: K = key @ Wk
        {
            bf16x8 afK[4];
            #pragma unroll
            for (int ks = 0; ks < 4; ++ks) {
                float t[8] = {0.f,0.f,0.f,0.f,0.f,0.f,0.f,0.f};
                if (rowok) {
                    *(float4*)&t[0] = *(const float4*)&key[(size_t)arow * DIM + ks * 32 + lg * 8];
                    *(float4*)&t[4] = *(const float4*)&key[(size_t)arow * DIM + ks * 32 + lg * 8 + 4];
                }
                union { bf16x8 v; unsigned u[4]; } a;
                a.u[0] = cvt_pk_bf16(t[0], t[1]);
                a.u[1] = cvt_pk_bf16(t[2], t[3]);
                a.u[2] = cvt_pk_bf16(t[4], t[5]);
                a.u[3] = cvt_pk_bf16(t[6], t[7]);
                afK[ks] = a.v;
            }
            #pragma unroll 2
            for (int ct = 0; ct < 8; ++ct) {
                f32x4 ack = (f32x4)0.f;
                #pragma unroll
                for (int ks = 0; ks < 4; ++ks) {
                    const size_t bo = (size_t)((ks * 8 + ct) * 64 + lane) * 8;
                    ack = __builtin_amdgcn_mfma_f32_16x16x32_bf16(afK[ks], *(const bf16x8*)&Wkp[bo], ack, 0, 0, 0);
                }
                const int col = ct * 16 + lr;
                const float bkv = bk[col];
                #pragma unroll
                for (int r = 0; r < 4; ++r) {
                    const int row = lg * 4 + r;
                    const float kv = ack[r] + bkv;
                    const float kn = swz_xor1(kv);
                    if (evenlane) lds[wid][row][ct * 8 + (lr >> 1)] = cvt_pk_bf16(kv, kn);
                }
            }
            #pragma unroll
            for (int rr = 0; rr < 16; ++rr) {
                const int grow = row0 + rr;
                if (grow < M) kvout[(size_t)grow * 128 + lane] = lds[wid][rr][lane];
            }
        }
        // pass 2: V = value @ Wv
        {
            bf16x8 afV[4];
            #pragma unroll
            for (int ks = 0; ks < 4; ++ks) {
                float t[8] = {0.f,0.f,0.f,0.f,0.f,0.f,0.f,0.f};
                if (rowok) {
                    *(float4*)&t[0] = *(const float4*)&value[(size_t)arow * DIM + ks * 32 + lg * 8];
                    *(float4*)&t[4] = *(const float4*)&value[(size_t)arow * DIM + ks * 32 + lg * 8 + 4];
                }
                union { bf16x8 v; unsigned u[4]; } a;
                a.u[0] = cvt_pk_bf16(t[0], t[1]);
                a.u[1] = cvt_pk_bf16(t[2], t[3]);
                a.u[2] = cvt_pk_bf16(t[4], t[5]);
                a.u[3] = cvt_pk_bf16(t[6], t[7]);
                afV[ks] = a.v;
            }
            #pragma unroll 2
            for (int ct = 0; ct < 8; ++ct) {
                f32x4 acv = (f32x4)0.f;
                #pragma unroll
                for (int ks = 0; ks < 4; ++ks) {
                    const size_t bo = (size_t)((ks * 8 + ct) * 64 + lane) * 8;
                    acv = __builtin_amdgcn_mfma_f32_16x16x32_bf16(afV[ks], *(const bf16x8*)&Wvp[bo], acv, 0, 0, 0);
                }
                const int col = ct * 16 + lr;
                const float bvv = bv[col];
                #pragma unroll
                for (int r = 0; r < 4; ++r) {
                    const int row = lg * 4 + r;
                    const float vv = acv[r] + bvv;
                    const float vn = swz_xor1(vv);
                    if (evenlane) lds[wid][row][ct * 8 + (lr >> 1)] = cvt_pk_bf16(vv, vn);
                }
            }
            #pragma unroll
            for (int rr = 0; rr < 16; ++rr) {
                const int grow = row0 + rr;
                if (grow < M) kvout[(size_t)grow * 128 + 64 + lane] = lds[wid][rr][lane];
            }
        }
    }
}

// ------------------------------------------------------------------
// CSR scan chain
// ------------------------------------------------------------------
__global__ __launch_bounds__(256) void scan1_kernel(const int* __restrict__ counts,
                                                    int* __restrict__ bsum, int N)
{
    __shared__ int sh[256];
    int i = blockIdx.x * 256 + threadIdx.x;
    sh[threadIdx.x] = (i < N) ? counts[i] : 0;
    __syncthreads();
    #pragma unroll
    for (int off = 128; off; off >>= 1) {
        if (threadIdx.x < off) sh[threadIdx.x] += sh[threadIdx.x + off];
        __syncthreads();
    }
    if (threadIdx.x == 0) bsum[blockIdx.x] = sh[0];
}

__global__ __launch_bounds__(256) void scan2_kernel(const int* __restrict__ bsum,
                                                    int* __restrict__ boff, int B)
{
    int t = threadIdx.x;
    if (B > 256) {
        if (t == 0) { int run = 0; for (int i = 0; i < B; ++i) { int v = bsum[i]; boff[i] = run; run += v; } }
        return;
    }
    __shared__ int sh[256];
    int v = (t < B) ? bsum[t] : 0;
    sh[t] = v;
    __syncthreads();
    for (int off = 1; off < 256; off <<= 1) {
        int x = (t >= off) ? sh[t - off] : 0;
        __syncthreads();
        sh[t] += x;
        __syncthreads();
    }
    if (t < B) boff[t] = sh[t] - v;
}

__global__ __launch_bounds__(256) void scan3_kernel(const int* __restrict__ counts,
                                                    const int* __restrict__ boff,
                                                    int* __restrict__ offsets,
                                                    int* __restrict__ cursor,
                                                    int N, int E)
{
    __shared__ int sh[256];
    int t = threadIdx.x;
    int i = blockIdx.x * 256 + t;
    int v = (i < N) ? counts[i] : 0;
    sh[t] = v;
    __syncthreads();
    for (int off = 1; off < 256; off <<= 1) {
        int x = (t >= off) ? sh[t - off] : 0;
        __syncthreads();
        sh[t] += x;
        __syncthreads();
    }
    int base = boff[blockIdx.x];
    if (i < N) {
        int o = base + sh[t] - v;
        offsets[i] = o;
        cursor[i] = o;
    }
    if (i == 0) offsets[N] = E;
}

__global__ void fill_kernel(const int* __restrict__ qidx, const int* __restrict__ kidx,
                            int* __restrict__ cursor, int* __restrict__ ksorted, int E)
{
    for (int e = blockIdx.x * blockDim.x + threadIdx.x; e < E; e += gridDim.x * blockDim.x) {
        int q = qidx[e];
        int pos = atomicAdd(&cursor[q], 1);
        ksorted[pos] = kidx[e];
    }
}

// ------------------------------------------------------------------
// Edge aggregation v9: one node per wave, 4 edge slots,
// DEPTH-4 software pipeline with 2-level index prefetch:
//   - T = ceil(deg/4) iterations (wave-uniform counted loop)
//   - 4 named stage buffers; each reloaded 4 stages ahead
//   - ksorted indices prefetched 8 stages ahead (row-load issue
//     never waits on the index load)
//   - in flight per wave: 8 row loads + 4 index loads
// ------------------------------------------------------------------
__global__ __launch_bounds__(256) void edge_agg_kernel(
    const short* __restrict__ QV16, const float* __restrict__ attnqq4,
    const short* __restrict__ KV16,
    const int* __restrict__ ksorted, const int* __restrict__ offsets,
    const float* __restrict__ avec, const float* __restrict__ alpha_p,
    short* __restrict__ msgn16, int N)
{
    const int lane = threadIdx.x & 63;
    const int wid  = threadIdx.x >> 6;
    const int e    = lane >> 4;         // edge slot 0..3
    const int sub  = lane & 15;         // 8-dim chunk
    const int h    = sub >> 1;          // head

    const float al = alpha_p[0];
    const float r  = (1.f - al) / (1.f + al);
    const float s1 = (1.f + al) * 0.5f;

    float c[8];
    {
        const float4 a0 = *(const float4*)&avec[sub * 8];
        const float4 a1 = *(const float4*)&avec[sub * 8 + 4];
        c[0] = a0.x * s1; c[1] = a0.y * s1; c[2] = a0.z * s1; c[3] = a0.w * s1;
        c[4] = a1.x * s1; c[5] = a1.y * s1; c[6] = a1.z * s1; c[7] = a1.w * s1;
    }

    const int wavesTotal = gridDim.x * 4;

    for (int n = blockIdx.x * 4 + wid; n < N; n += wavesTotal) {
        float q[8];
        {
            unsigned qd[4];
            *(uint4*)qd = *(const uint4*)&QV16[(size_t)n * 256 + sub * 8];
            #pragma unroll
            for (int j = 0; j < 4; ++j) { q[2*j] = bflo(qd[j]); q[2*j+1] = bfhi(qd[j]); }
        }

        float acc[8];
        float den;
        if (e == 0) {
            unsigned vdi[4];
            *(uint4*)vdi = *(const uint4*)&QV16[(size_t)n * 256 + 128 + sub * 8];
            #pragma unroll
            for (int j = 0; j < 4; ++j) { acc[2*j] = bflo(vdi[j]); acc[2*j+1] = bfhi(vdi[j]); }
            den = 1.f;
        } else {
            #pragma unroll
            for (int d = 0; d < 8; ++d) acc[d] = 0.f;
            den = 0.f;
        }

        float m;
        {
            const float4 a4 = *(const float4*)&attnqq4[(size_t)n * 32 + h * 4];
            m = (a4.x + a4.y) + (a4.z + a4.w);
        }

        const int p0 = offsets[n];
        const int p1 = offsets[n + 1];
        const int T  = (p1 - p0 + 3) >> 2;   // wave-uniform iteration count
        bool div = false;

        #define ROWLOAD(kd_, vd_, ki_)                                        \
            {                                                                 \
                const size_t kb = (size_t)(ki_) * 256 + sub * 8;              \
                *(uint4*)(kd_) = *(const uint4*)&KV16[kb];                    \
                *(uint4*)(vd_) = *(const uint4*)&KV16[kb + 128];              \
            }

        unsigned kdA[4], vdA[4], kdB[4], vdB[4];
        unsigned kdC[4], vdC[4], kdD[4], vdD[4];
        bool vA, vB, vC, vD;
        int kiA, kiB, kiC, kiD;   // indices for stages t+4..t+7

        // prologue: rows for stages 0..3, indices for stages 4..7
        {
            int i0 = p0 + e,      i1 = p0 + 4 + e;
            int i2 = p0 + 8 + e,  i3 = p0 + 12 + e;
            vA = i0 < p1; vB = i1 < p1; vC = i2 < p1; vD = i3 < p1;
            const int k0 = vA ? ksorted[i0] : 0;
            const int k1 = vB ? ksorted[i1] : 0;
            const int k2 = vC ? ksorted[i2] : 0;
            const int k3 = vD ? ksorted[i3] : 0;
            ROWLOAD(kdA, vdA, k0); ROWLOAD(kdB, vdB, k1);
            ROWLOAD(kdC, vdC, k2); ROWLOAD(kdD, vdD, k3);
            int j0 = p0 + 16 + e, j1 = p0 + 20 + e;
            int j2 = p0 + 24 + e, j3 = p0 + 28 + e;
            kiA = (j0 < p1) ? ksorted[j0] : 0;
            kiB = (j1 < p1) ? ksorted[j1] : 0;
            kiC = (j2 < p1) ? ksorted[j2] : 0;
            kiD = (j3 < p1) ? ksorted[j3] : 0;
        }

        #define COMPUTE(kd_, vd_, vflag)                                      \
            {                                                                 \
                float sp = 0.f;                                               \
                _Pragma("unroll")                                             \
                for (int j = 0; j < 4; ++j) {                                 \
                    const float x0 = q[2*j]   + bflo(kd_[j]);                 \
                    const float x1 = q[2*j+1] + bfhi(kd_[j]);                 \
                    const float t0 = fmaf(r, __builtin_fabsf(x0), x0);        \
                    const float t1 = fmaf(r, __builtin_fabsf(x1), x1);        \
                    sp = fmaf(c[2*j], t0, sp);                                \
                    sp = fmaf(c[2*j+1], t1, sp);                              \
                }                                                             \
                const float sf = sp + swz_xor1(sp);                           \
                const float s = (vflag) ? sf : NEGINF;                        \
                const float d_ = s - m;                                       \
                if (__any(d_ > 8.f)) {                                        \
                    div = true;                                               \
                    const float nm = fmaxf(m, s);                             \
                    const float cc = __expf(m - nm);                          \
                    const float w = __expf(s - nm);                           \
                    den = den * cc + w;                                       \
                    _Pragma("unroll")                                         \
                    for (int j = 0; j < 4; ++j) {                             \
                        acc[2*j]   = fmaf(acc[2*j],   cc, w * bflo(vd_[j])); \
                        acc[2*j+1] = fmaf(acc[2*j+1], cc, w * bfhi(vd_[j])); \
                    }                                                         \
                    m = nm;                                                   \
                } else {                                                      \
                    const float w = __expf(d_);                               \
                    den += w;                                                 \
                    _Pragma("unroll")                                         \
                    for (int j = 0; j < 4; ++j) {                             \
                        acc[2*j]   = fmaf(w, bflo(vd_[j]), acc[2*j]);         \
                        acc[2*j+1] = fmaf(w, bfhi(vd_[j]), acc[2*j+1]);       \
                    }                                                         \
                }                                                             \
            }

        #define RELOAD(kd_, vd_, vflag, ki_, st4, st8)                        \
            {                                                                 \
                vflag = (p0 + (st4) * 4 + e) < p1;                            \
                ROWLOAD(kd_, vd_, ki_);                                       \
                const int fi = p0 + (st8) * 4 + e;                            \
                ki_ = (fi < p1) ? ksorted[fi] : 0;                            \
            }

        #pragma unroll 1
        for (int t = 0; t < T; t += 4) {
            COMPUTE(kdA, vdA, vA); RELOAD(kdA, vdA, vA, kiA, t + 4, t + 8);
            COMPUTE(kdB, vdB, vB); RELOAD(kdB, vdB, vB, kiB, t + 5, t + 9);
            COMPUTE(kdC, vdC, vC); RELOAD(kdC, vdC, vC, kiC, t + 6, t + 10);
            COMPUTE(kdD, vdD, vD); RELOAD(kdD, vdD, vD, kiD, t + 7, t + 11);
        }
        #undef COMPUTE
        #undef RELOAD
        #undef ROWLOAD

        // merge 4 slots: lane bit 4 (xor16, within half) then bit 5 (xor32)
        #define MERGE_ROUND(SWZ)                                    \
            {                                                       \
                const float m2 = SWZ(m);                            \
                const float den2 = SWZ(den);                        \
                const float nm = fmaxf(m, m2);                      \
                const float ca = __expf(m - nm);                    \
                const float cb = __expf(m2 - nm);                   \
                den = den * ca + den2 * cb;                         \
                _Pragma("unroll")                                   \
                for (int d = 0; d < 8; ++d)                         \
                    acc[d] = acc[d] * ca + SWZ(acc[d]) * cb;        \
                m = nm;                                             \
            }
        #define SUM_ROUND(SWZ)                                      \
            {                                                       \
                den += SWZ(den);                                    \
                _Pragma("unroll")                                   \
                for (int d = 0; d < 8; ++d) acc[d] += SWZ(acc[d]);  \
            }
        if (div) {
            MERGE_ROUND(swz_xor16);
            MERGE_ROUND(swz_xor32);
        } else {
            SUM_ROUND(swz_xor16);
            SUM_ROUND(swz_xor32);
        }
        #undef MERGE_ROUND
        #undef SUM_ROUND

        if (e == 0) {
            const float inv = 1.f / den;
            unsigned u[4];
            #pragma unroll
            for (int j = 0; j < 4; ++j)
                u[j] = cvt_pk_bf16(acc[2*j] * inv, acc[2*j+1] * inv);
            *(uint4*)&msgn16[(size_t)n * DIM + sub * 8] = *(uint4*)u;
        }
    }
}

// ------------------------------------------------------------------
// Output projection (MFMA, unroll-2 ct chains) + residual + LayerNorm.
// ------------------------------------------------------------------
__global__ __launch_bounds__(256) void out_ln_mfma(
    const short* __restrict__ msgn16, const short* __restrict__ Wpp,
    const float* __restrict__ bp, const float* __restrict__ query,
    const float* __restrict__ gamma, const float* __restrict__ beta,
    float* __restrict__ out, int N)
{
    __shared__ float ys[64][130];
    const int wid = threadIdx.x >> 6, lane = threadIdx.x & 63;
    const int rowbase = blockIdx.x * 64;
    const int row0 = rowbase + wid * 16;
    const int lr = lane & 15, lg = lane >> 4;

    if (row0 < N) {
        bf16x8 afrag[4];
        const int arow = row0 + lr;
        const bool rowok = arow < N;
        #pragma unroll
        for (int ks = 0; ks < 4; ++ks) {
            if (rowok)
                afrag[ks] = *(const bf16x8*)&msgn16[(size_t)arow * DIM + ks * 32 + lg * 8];
            else {
                bf16x8 z;
                #pragma unroll
                for (int j = 0; j < 8; ++j) z[j] = 0;
                afrag[ks] = z;
            }
        }
        #pragma unroll 2
        for (int ct = 0; ct < 8; ++ct) {
            f32x4 acc = (f32x4)0.f;
            #pragma unroll
            for (int ks = 0; ks < 4; ++ks) {
                const size_t bo = (size_t)((ks * 8 + ct) * 64 + lane) * 8;
                acc = __builtin_amdgcn_mfma_f32_16x16x32_bf16(afrag[ks], *(const bf16x8*)&Wpp[bo], acc, 0, 0, 0);
            }
            const int col = ct * 16 + lr;
            const float bpv = bp[col];
            #pragma unroll
            for (int r = 0; r < 4; ++r)
                ys[wid * 16 + lg * 4 + r][col] = acc[r] + bpv;
        }
    }
    __syncthreads();

    for (int rr = 0; rr < 16; ++rr) {
        const int r = wid * 16 + rr;
        const int grow = rowbase + r;
        if (grow >= N) break;
        const float y1 = ys[r][lane], y2 = ys[r][lane + 64];
        const float q1 = query[(size_t)grow * DIM + lane];
        const float q2 = query[(size_t)grow * DIM + lane + 64];
        const float r1 = y1 + q1, r2 = y2 + q2;
        float s = r1 + r2;
        float ss = r1 * r1 + r2 * r2;
        #pragma unroll
        for (int off = 32; off; off >>= 1) {
            s += __shfl_xor(s, off);
            ss += __shfl_xor(ss, off);
        }
        const float mu = s * (1.f / DIM);
        const float var = ss * (1.f / DIM) - mu * mu;
        const float rstd = rsqrtf(var + LN_EPS);
        out[(size_t)grow * DIM + lane] = gamma[lane] * (r1 - mu) * rstd + beta[lane];
        out[(size_t)grow * DIM + lane + 64] = gamma[lane + 64] * (r2 - mu) * rstd + beta[lane + 64];
    }
}

// ------------------------------------------------------------------
extern "C" void kernel_launch(void* const* d_in, const int* in_sizes, int n_in,
                              void* d_out, int out_size, void* d_ws, size_t ws_size,
                              hipStream_t stream) {
    const float* query = (const float*)d_in[0];
    const float* key   = (const float*)d_in[1];
    const float* value = (const float*)d_in[2];
    const int* query_idx = (const int*)d_in[3];
    const int* key_idx   = (const int*)d_in[4];
    const float* Wq = (const float*)d_in[5];
    const float* bq = (const float*)d_in[6];
    const float* Wk = (const float*)d_in[7];
    const float* bk = (const float*)d_in[8];
    const float* Wv = (const float*)d_in[9];
    const float* bv = (const float*)d_in[10];
    const float* Wp = (const float*)d_in[11];
    const float* bp = (const float*)d_in[12];
    const float* avec  = (const float*)d_in[13];
    const float* alpha = (const float*)d_in[14];
    const float* gamma = (const float*)d_in[15];
    const float* beta  = (const float*)d_in[16];
    float* out = (float*)d_out;

    const int N = in_sizes[0] / DIM;
    const int M = in_sizes[1] / DIM;
    const int E = in_sizes[3];

    // workspace layout (16B aligned)
    float* f = (float*)d_ws;
    float* attnqq4 = f; f += (size_t)N * 32;
    short* sp = (short*)f;
    short* QV16 = sp;   sp += (size_t)N * 256;
    short* KV16 = sp;   sp += (size_t)M * 256;
    short* msgn16 = sp; sp += (size_t)N * DIM;
    short* Wqp = sp;    sp += DIM * DIM;
    short* Wkp = sp;    sp += DIM * DIM;
    short* Wvp = sp;    sp += DIM * DIM;
    short* Wpp = sp;    sp += DIM * DIM;
    int* ip = (int*)(((size_t)sp + 15) & ~(size_t)15);
    int* counts  = ip;  ip += N;
    int* offsets = ip;  ip += N + 1;
    int* cursor  = ip;  ip += N;
    int* bsum    = ip;  ip += 4096;
    int* boff    = ip;  ip += 4096;
    int* ksorted = ip;  ip += E;

    const int B = (N + 255) / 256;
    const int nb = (N + 63) / 64;
    const int mb = (M + 63) / 64;

    hipMemsetAsync(counts, 0, (size_t)N * sizeof(int), stream);

    setup_kernel<<<1056, 256, 0, stream>>>(Wq, Wk, Wv, Wp, Wqp, Wkp, Wvp, Wpp,
                                           query_idx, counts, E);

    scan1_kernel<<<B, 256, 0, stream>>>(counts, bsum, N);
    scan2_kernel<<<1, 256, 0, stream>>>(bsum, boff, B);
    scan3_kernel<<<B, 256, 0, stream>>>(counts, boff, offsets, cursor, N, E);
    fill_kernel<<<1024, 256, 0, stream>>>(query_idx, key_idx, cursor, ksorted, E);

    proj_all_mfma<<<nb + mb, 256, 0, stream>>>(
        query, key, value, Wqp, Wkp, Wvp, bq, bk, bv, avec, alpha,
        QV16, attnqq4, KV16, N, M, nb);

    edge_agg_kernel<<<2048, 256, 0, stream>>>(
        QV16, attnqq4, KV16, ksorted, offsets, avec, alpha, msgn16, N);

    out_ln_mfma<<<(N + 63) / 64, 256, 0, stream>>>(
        msgn16, Wpp, bp, query, gamma, beta, out, N);
}